// Round 6
// baseline (231.056 us; speedup 1.0000x reference)
//
#include <hip/hip_runtime.h>
#include <hip/hip_bf16.h>

// streams: x250 (len 15000, step 4), x500 (len 30000, step 2), x1000 (len 60000, step 1)
// L = 60000, D_MODEL = 256, KERNEL = 5 taps, pad = 2. Inputs fp32, output fp32.
// Output layout (flat fp32): X [3,256,60000] = 46,080,000 elems; S [2,60000] = 120,000.
// Conv collapses per stream (zero-insertion upsample):
//   i=0: y = b + w2*x250[p]                                  (p<15000)
//   i=1: y = b + w0*x500[p-1] + w2*x500[p] + w4*x500[p+1]    (p<30000)
//   i=2: full 5-tap on x1000                                 (p<60000)
// Persistent row-blocks: grid (2,256,3) = 1536 blocks = 6 blocks/CU; each block
// streams a contiguous 120KB half-row through 15 iterations of nt stores.

#define L_OUT   60000
#define LEN0    15000
#define LEN1    30000
#define LEN2    60000
#define DMODEL  256
#define X_ELEMS (3 * DMODEL * L_OUT)
#define HALF    30000

typedef float float4v __attribute__((ext_vector_type(4)));  // clang vector: nt-store OK

__device__ __forceinline__ float ld_or_zero(const float* __restrict__ x,
                                            int idx, int len) {
    return (idx >= 0 && idx < len) ? x[idx] : 0.0f;
}

__device__ __forceinline__ void st_nt4(float* p, float a, float b, float c, float d) {
    float4v v; v.x = a; v.y = b; v.z = c; v.w = d;
    __builtin_nontemporal_store(v, (float4v*)p);
}

__global__ __launch_bounds__(256) void conv_rows_kernel(
    const float* __restrict__ x250,
    const float* __restrict__ x500,
    const float* __restrict__ x1000,
    const float* __restrict__ W,   // [256,1,5]
    const float* __restrict__ b,   // [256]
    float* __restrict__ out)
{
    const int half = blockIdx.x;   // 0..1  -> positions [half*30000, half*30000+30000)
    const int c    = blockIdx.y;   // 0..255
    const int i    = blockIdx.z;   // 0..2
    const int tid  = threadIdx.x;

    const float w0 = W[c * 5 + 0];
    const float w1 = W[c * 5 + 1];
    const float w2 = W[c * 5 + 2];
    const float w3 = W[c * 5 + 3];
    const float w4 = W[c * 5 + 4];
    const float bias = b[c];

    float* __restrict__ row = out + (size_t)(i * DMODEL + c) * L_OUT;
    const int pbase = half * HALF;
    const int pend  = pbase + HALF;

    if (i == 0) {
#pragma unroll 1
        for (int it = 0; it < 15; ++it) {
            const int p0 = pbase + it * 2048 + tid * 8;
            if (p0 >= pend) continue;          // only last-iteration tail
            float y[8];
            if (p0 + 8 <= LEN0) {
#pragma unroll
                for (int j = 0; j < 8; ++j) y[j] = fmaf(w2, x250[p0 + j], bias);
            } else if (p0 >= LEN0) {
#pragma unroll
                for (int j = 0; j < 8; ++j) y[j] = 0.0f;
            } else {
#pragma unroll
                for (int j = 0; j < 8; ++j) {
                    const int p = p0 + j;
                    y[j] = (p < LEN0) ? fmaf(w2, x250[p], bias) : 0.0f;
                }
            }
            st_nt4(row + p0,     y[0], y[1], y[2], y[3]);
            st_nt4(row + p0 + 4, y[4], y[5], y[6], y[7]);
        }
    } else if (i == 1) {
#pragma unroll 1
        for (int it = 0; it < 15; ++it) {
            const int p0 = pbase + it * 2048 + tid * 8;
            if (p0 >= pend) continue;
            float y[8];
            if (p0 >= 1 && p0 + 9 <= LEN1) {   // interior: needs p0-1 .. p0+8
#pragma unroll
                for (int j = 0; j < 8; ++j) {
                    const int p = p0 + j;
                    float acc = fmaf(w0, x500[p - 1], bias);
                    acc = fmaf(w2, x500[p], acc);
                    acc = fmaf(w4, x500[p + 1], acc);
                    y[j] = acc;
                }
            } else if (p0 >= LEN1) {
#pragma unroll
                for (int j = 0; j < 8; ++j) y[j] = 0.0f;
            } else {
#pragma unroll
                for (int j = 0; j < 8; ++j) {
                    const int p = p0 + j;
                    if (p < LEN1) {
                        float acc = fmaf(w0, ld_or_zero(x500, p - 1, LEN1), bias);
                        acc = fmaf(w2, x500[p], acc);
                        acc = fmaf(w4, ld_or_zero(x500, p + 1, LEN1), acc);
                        y[j] = acc;
                    } else {
                        y[j] = 0.0f;
                    }
                }
            }
            st_nt4(row + p0,     y[0], y[1], y[2], y[3]);
            st_nt4(row + p0 + 4, y[4], y[5], y[6], y[7]);
        }
    } else {
#pragma unroll 1
        for (int it = 0; it < 15; ++it) {
            const int p0 = pbase + it * 2048 + tid * 8;
            if (p0 >= pend) continue;
            float y[8];
            if (p0 >= 2 && p0 + 10 <= LEN2) {  // interior: needs p0-2 .. p0+9
#pragma unroll
                for (int j = 0; j < 8; ++j) {
                    const int p = p0 + j;
                    float acc = fmaf(w0, x1000[p - 2], bias);
                    acc = fmaf(w1, x1000[p - 1], acc);
                    acc = fmaf(w2, x1000[p], acc);
                    acc = fmaf(w3, x1000[p + 1], acc);
                    acc = fmaf(w4, x1000[p + 2], acc);
                    y[j] = acc;
                }
            } else {
#pragma unroll
                for (int j = 0; j < 8; ++j) {
                    const int p = p0 + j;
                    float acc = fmaf(w0, ld_or_zero(x1000, p - 2, LEN2), bias);
                    acc = fmaf(w1, ld_or_zero(x1000, p - 1, LEN2), acc);
                    acc = fmaf(w2, x1000[p], acc);
                    acc = fmaf(w3, ld_or_zero(x1000, p + 1, LEN2), acc);
                    acc = fmaf(w4, ld_or_zero(x1000, p + 2, LEN2), acc);
                    y[j] = acc;
                }
            }
            st_nt4(row + p0,     y[0], y[1], y[2], y[3]);
            st_nt4(row + p0 + 4, y[4], y[5], y[6], y[7]);
        }
    }
}

__global__ __launch_bounds__(256) void s_kernel(float* __restrict__ out_s)
{
    const int v = blockIdx.x * 256 + threadIdx.x;
    if (v >= (2 * L_OUT) / 4) return;   // 30000 float4 stores
    const int t0 = v * 4;

    float ov[4];
#pragma unroll
    for (int j = 0; j < 4; ++j) {
        const int t = t0 + j;
        float val;
        if (t < L_OUT) {
            val = (t < 15000) ? 0.0f : ((t < 45000) ? 1.0f : 2.0f);   // rows
        } else {
            const int u = t - L_OUT;                                  // cols
            int iv;
            if (u < 15000)      iv = 4 * u;
            else if (u < 45000) iv = 2 * (u - 15000);
            else                iv = u - 45000;
            val = (float)iv;
        }
        ov[j] = val;
    }
    st_nt4(out_s + t0, ov[0], ov[1], ov[2], ov[3]);
}

extern "C" void kernel_launch(void* const* d_in, const int* in_sizes, int n_in,
                              void* d_out, int out_size, void* d_ws, size_t ws_size,
                              hipStream_t stream) {
    const float* x250  = (const float*)d_in[0];
    const float* x500  = (const float*)d_in[1];
    const float* x1000 = (const float*)d_in[2];
    const float* W     = (const float*)d_in[3];
    const float* b     = (const float*)d_in[4];
    float* out = (float*)d_out;

    dim3 grid_x(2, DMODEL, 3);   // 1536 persistent row-blocks = 6 blocks/CU
    conv_rows_kernel<<<grid_x, 256, 0, stream>>>(x250, x500, x1000, W, b, out);

    s_kernel<<<(30000 + 255) / 256, 256, 0, stream>>>(out + X_ELEMS);
}

// Round 7
// 196.607 us; speedup vs baseline: 1.1752x; 1.1752x over previous
//
#include <hip/hip_runtime.h>
#include <hip/hip_bf16.h>

// streams: x250 (len 15000, step 4), x500 (len 30000, step 2), x1000 (len 60000, step 1)
// L = 60000, D_MODEL = 256, KERNEL = 5 taps, pad = 2. Inputs fp32, output fp32.
// Output (flat fp32): X [3,256,60000] = 46,080,000 elems; S [2,60000] = 120,000.
// Conv collapses per stream (zero-insertion upsample):
//   i=0: y = b + w2*x[p]                       (p<15000)
//   i=1: y = b + w0*x[p-1] + w2*x[p] + w4*x[p+1]   (p<30000)
//   i=2: full 5-tap                            (p<60000)
// Channel-amortized blocks: each block caches its x window in registers once,
// then loops 32 channels -> 128KB written per block setup. S fused (cg==8).

#define L_OUT   60000
#define LEN0    15000
#define LEN1    30000
#define LEN2    60000
#define DMODEL  256
#define X_ELEMS (3 * DMODEL * L_OUT)

typedef float float4v __attribute__((ext_vector_type(4)));

__device__ __forceinline__ void st_nt4(float* p, float a, float b, float c, float d) {
    float4v v; v.x = a; v.y = b; v.z = c; v.w = d;
    __builtin_nontemporal_store(v, (float4v*)p);
}

__device__ __forceinline__ float ld_or_zero(const float* __restrict__ x,
                                            int idx, int len) {
    return (idx >= 0 && idx < len) ? x[idx] : 0.0f;
}

// grid: (59 chunks of 1024 pos, 9, 3 streams) x 256 threads.
// blockIdx.y in [0,8): 32-channel group; ==8: S-output duty.
__global__ __launch_bounds__(256) void embed_kernel(
    const float* __restrict__ x250,
    const float* __restrict__ x500,
    const float* __restrict__ x1000,
    const float* __restrict__ W,   // [256,1,5]
    const float* __restrict__ b,   // [256]
    float* __restrict__ out)
{
    const int chunk = blockIdx.x;   // 0..58
    const int cg    = blockIdx.y;   // 0..8
    const int i     = blockIdx.z;   // 0..2
    const int tid   = threadIdx.x;

    if (cg == 8) {
        // ---- S duty: 177 blocks cover 120000 elems, 4/thread ----
        const int sid = i * 59 + chunk;
        const int t0  = sid * 1024 + tid * 4;
        if (t0 >= 2 * L_OUT) return;
        float ov[4];
#pragma unroll
        for (int j = 0; j < 4; ++j) {
            const int t = t0 + j;
            float val;
            if (t < L_OUT) {
                val = (t < 15000) ? 0.0f : ((t < 45000) ? 1.0f : 2.0f);  // rows
            } else {
                const int u = t - L_OUT;                                 // cols
                int iv;
                if (u < 15000)      iv = 4 * u;
                else if (u < 45000) iv = 2 * (u - 15000);
                else                iv = u - 45000;
                val = (float)iv;
            }
            ov[j] = val;
        }
        st_nt4(out + X_ELEMS + t0, ov[0], ov[1], ov[2], ov[3]);
        return;
    }

    const int p0 = chunk * 1024 + tid * 4;
    if (p0 >= L_OUT) return;        // only chunk 58 tail threads

    const int cbase = cg * 32;
    float* dst = out + (size_t)(i * DMODEL + cbase) * L_OUT + p0;
    const int len = (i == 0) ? LEN0 : (i == 1) ? LEN1 : LEN2;

    if (p0 >= len) {
        // ---- pure-zero duty (42% of X bytes): no loads, 32 nt stores ----
#pragma unroll 4
        for (int ci = 0; ci < 32; ++ci) { st_nt4(dst, 0.f, 0.f, 0.f, 0.f); dst += L_OUT; }
        return;
    }
    // NOTE: len is a multiple of 4 and p0 is a multiple of 4, so p0 < len
    // implies p0+3 < len — no per-position masking needed below.

    if (i == 0) {
        float xv[4];
#pragma unroll
        for (int j = 0; j < 4; ++j) xv[j] = x250[p0 + j];
#pragma unroll 4
        for (int ci = 0; ci < 32; ++ci) {
            const int c = cbase + ci;
            const float w2 = W[c * 5 + 2], bias = b[c];
            float y[4];
#pragma unroll
            for (int j = 0; j < 4; ++j) y[j] = fmaf(w2, xv[j], bias);
            st_nt4(dst, y[0], y[1], y[2], y[3]);
            dst += L_OUT;
        }
    } else if (i == 1) {
        float a[6];                              // x500[p0-1 .. p0+4]
#pragma unroll
        for (int j = 0; j < 6; ++j) a[j] = ld_or_zero(x500, p0 - 1 + j, LEN1);
#pragma unroll 4
        for (int ci = 0; ci < 32; ++ci) {
            const int c = cbase + ci;
            const float w0 = W[c * 5 + 0], w2 = W[c * 5 + 2],
                        w4 = W[c * 5 + 4], bias = b[c];
            float y[4];
#pragma unroll
            for (int j = 0; j < 4; ++j) {
                float acc = fmaf(w0, a[j], bias);     // x[p-1]
                acc = fmaf(w2, a[j + 1], acc);        // x[p]
                acc = fmaf(w4, a[j + 2], acc);        // x[p+1]
                y[j] = acc;
            }
            st_nt4(dst, y[0], y[1], y[2], y[3]);
            dst += L_OUT;
        }
    } else {
        float a[8];                              // x1000[p0-2 .. p0+5]
#pragma unroll
        for (int j = 0; j < 8; ++j) a[j] = ld_or_zero(x1000, p0 - 2 + j, LEN2);
#pragma unroll 4
        for (int ci = 0; ci < 32; ++ci) {
            const int c = cbase + ci;
            const float w0 = W[c * 5 + 0], w1 = W[c * 5 + 1], w2 = W[c * 5 + 2],
                        w3 = W[c * 5 + 3], w4 = W[c * 5 + 4], bias = b[c];
            float y[4];
#pragma unroll
            for (int j = 0; j < 4; ++j) {
                float acc = fmaf(w0, a[j], bias);
                acc = fmaf(w1, a[j + 1], acc);
                acc = fmaf(w2, a[j + 2], acc);
                acc = fmaf(w3, a[j + 3], acc);
                acc = fmaf(w4, a[j + 4], acc);
                y[j] = acc;
            }
            st_nt4(dst, y[0], y[1], y[2], y[3]);
            dst += L_OUT;
        }
    }
}

extern "C" void kernel_launch(void* const* d_in, const int* in_sizes, int n_in,
                              void* d_out, int out_size, void* d_ws, size_t ws_size,
                              hipStream_t stream) {
    const float* x250  = (const float*)d_in[0];
    const float* x500  = (const float*)d_in[1];
    const float* x1000 = (const float*)d_in[2];
    const float* W     = (const float*)d_in[3];
    const float* b     = (const float*)d_in[4];
    float* out = (float*)d_out;

    // 59 position chunks x (8 channel groups + 1 S duty) x 3 streams
    dim3 grid(59, 9, 3);
    embed_kernel<<<grid, 256, 0, stream>>>(x250, x500, x1000, W, b, out);
}